// Round 2
// baseline (82.866 us; speedup 1.0000x reference)
//
#include <hip/hip_runtime.h>

#define K      32
#define KQ     8                    // bins per lane (K split across lane QUADS)
#define TPB    256
#define NB     2048                 // 2048 blocks * 64 quad-slots * 16 = N
#define EPT    16                   // elements per quad-slot
#define NTOT   (32 * 64 * 1024)     // 2,097,152
#define PSTRIDE (NB * (TPB / 4))    // 131072 quad-slots per sweep

__device__ __forceinline__ float wave_reduce_sum(float v) {
#pragma unroll
  for (int m = 1; m < 64; m <<= 1) v += __shfl_xor(v, m, 64);
  return v;
}

// xor-1 neighbor add via DPP quad_perm(1,0,3,2): VALU-only, no LDS pipe.
__device__ __forceinline__ float dpp_xor1_add(float v) {
  int sw = __builtin_amdgcn_update_dpp(0, __builtin_bit_cast(int, v),
                                       0xB1, 0xF, 0xF, true);
  return v + __builtin_bit_cast(float, sw);
}
// xor-2 via quad_perm(2,3,0,1) = 0x4E
__device__ __forceinline__ float dpp_xor2_add(float v) {
  int sw = __builtin_amdgcn_update_dpp(0, __builtin_bit_cast(int, v),
                                       0x4E, 0xF, 0xF, true);
  return v + __builtin_bit_cast(float, sw);
}
// xor-8 via row_ror:8 (rotation by 8 within a 16-lane row == lane^8) = 0x128
__device__ __forceinline__ float dpp_xor8_add(float v) {
  int sw = __builtin_amdgcn_update_dpp(0, __builtin_bit_cast(int, v),
                                       0x128, 0xF, 0xF, true);
  return v + __builtin_bit_cast(float, sw);
}

// reduce across lanes of the SAME quad-position (16 lanes): masks 4,8,16,32.
// 8 is DPP row_ror (VALU); 4,16,32 stay shfl (no exact xor-DPP for them).
__device__ __forceinline__ float quad_lane_reduce(float v) {
  v += __shfl_xor(v, 4, 64);
  v = dpp_xor8_add(v);
  v += __shfl_xor(v, 16, 64);
  v += __shfl_xor(v, 32, 64);
  return v;
}

// Round-2 theory: R1 gained ~0. The main kernel (~38us vs ~10us issue floor)
// is latency-bound at 4 waves/SIMD: binv[16]+sAcc[16]+t[16]=48 array VGPRs
// put it in the 65-128 band. Fix: QUAD decomposition -- 4 lanes per element,
// 8 bins per lane. Arrays halve to 24 regs total (~50 VGPR) ->
// __launch_bounds__(256,8) pins 8 waves/SIMD; the 2048-block grid is then
// EXACTLY co-resident (256 CU x 8 blocks). Cross-lane combine is xor1+xor2,
// both quad_perm DPP (VALU-only). EPT 8->16 keeps grid/partials layout.
// e-loop stays 'unroll 1' (only proven-safe setting for the allocator).
__global__ __launch_bounds__(TPB, 8)
void ssq_main(const float* __restrict__ x, const float* __restrict__ bins,
              float* __restrict__ out, float* __restrict__ partials) {
  const int tid   = threadIdx.x;
  const int quarter = tid & 3;                    // which 8-bin quarter
  const int qslot = blockIdx.x * (TPB / 4) + (tid >> 2);

  // this lane's 8 bins (VGPRs -- quarter-dependent, can't be SGPR)
  float binv[KQ];
#pragma unroll
  for (int j = 0; j < KQ; ++j) binv[j] = bins[KQ * quarter + j];
  float bs_local = 0.f;
#pragma unroll
  for (int j = 0; j < KQ; ++j) bs_local += binv[j];
  const float binsum = dpp_xor2_add(dpp_xor1_add(bs_local)); // all 32 bins
  const float epsb = 1e-10f * binsum;             // eps * sum(bins) term

  float sAcc[KQ];
#pragma unroll
  for (int j = 0; j < KQ; ++j) sAcc[j] = 0.f;
  float q = 0.f;

  const float Ch = -7.213475204444817f;           // 0.5 * ALPHA * log2(e)

  float xv_cur = x[qslot];                        // 1-deep prefetch scalar

#pragma unroll 1
  for (int e = 0; e < EPT; ++e) {
    const float xv = xv_cur;
    if (e + 1 < EPT) xv_cur = x[qslot + (e + 1) * PSTRIDE];  // uniform branch
    float t[KQ];                                  // static indices only
    float s0 = 0.f, s1 = 0.f, h0 = 0.f, h1 = 0.f, b0 = 0.f, b1 = 0.f;
#pragma unroll
    for (int j = 0; j < KQ; j += 2) {
      float ha = __builtin_amdgcn_exp2f(Ch * fabsf(xv - binv[j + 0]));
      float hb = __builtin_amdgcn_exp2f(Ch * fabsf(xv - binv[j + 1]));
      float ta = ha * ha, tb = hb * hb;
      t[j + 0] = ta; t[j + 1] = tb;
      s0 += ta; s1 += tb;
      h0 += ha; h1 += hb;
      b0 = fmaf(ta, binv[j + 0], b0);
      b1 = fmaf(tb, binv[j + 1], b1);
    }
    const float s_loc = s0 + s1;
    const float b_loc = b0 + b1;
    // combine the 4 lanes of the quad: xor1 then xor2, both pure-VALU DPP
    const float s_full = dpp_xor2_add(dpp_xor1_add(s_loc));
    const float b_full = dpp_xor2_add(dpp_xor1_add(b_loc));
    const float inv = __builtin_amdgcn_rcpf(s_full);
    // local hsum * rsqrt(s): summing q over ALL lanes later gives sum_k sqrt(a_k)
    q = fmaf(h0 + h1, __builtin_amdgcn_rsqf(s_full), q);
    if (quarter == 0) out[qslot + e * PSTRIDE] = fmaf(b_full, inv, epsb);
#pragma unroll
    for (int j = 0; j < KQ; ++j) sAcc[j] = fmaf(t[j], inv, sAcc[j]);
  }

  // block reduction. Same-quad-position reduce (masks 4,8,16,32): after it,
  // lanes 0..3 hold the bin sums for quarters 0..3 (lane==quarter there).
  __shared__ float red[4][K + 1];
  const int lane = tid & 63, wv = tid >> 6;
#pragma unroll
  for (int j = 0; j < KQ; ++j) {
    float v = quad_lane_reduce(sAcc[j]);
    if (lane < 4) red[wv][KQ * lane + j] = v;     // lane==quarter here
  }
  {
    float v = wave_reduce_sum(q);
    if (lane == 0) red[wv][K] = v;
  }
  __syncthreads();
  if (tid < K + 1) {
    float v = red[0][tid] + red[1][tid] + red[2][tid] + red[3][tid];
    partials[tid * NB + blockIdx.x] = v;          // written exactly once
  }
}

// 33 blocks: block c reduces partials[c*NB .. c*NB+NB) -> sums[c]
__global__ __launch_bounds__(TPB)
void ssq_reduce(const float* __restrict__ partials, float* __restrict__ sums) {
  const float* p = partials + blockIdx.x * NB;
  const int tid  = threadIdx.x;
  float s = 0.f;
#pragma unroll
  for (int j = 0; j < NB / TPB; ++j) s += p[tid + j * TPB];
  s = wave_reduce_sum(s);
  __shared__ float red[4];
  if ((tid & 63) == 0) red[tid >> 6] = s;
  __syncthreads();
  if (tid == 0) sums[blockIdx.x] = red[0] + red[1] + red[2] + red[3];
}

// one wave: entropy over 32 p_k + quant mean + tails
__global__ void ssq_final(const float* __restrict__ sums, float* __restrict__ out) {
  const int lane = threadIdx.x;
  float e = 0.f;
  if (lane < K) {
    float p = sums[lane] * (1.0f / (float)NTOT) + 1e-10f;  // eps folded in here
    e = -p * __logf(p);
  }
  e = wave_reduce_sum(e);
  if (lane == 0) {
    out[NTOT + 0] = e;                              // code entropy
    out[NTOT + 1] = 0.f;                            // TAU
    out[NTOT + 2] = sums[K] * (1.0f / (float)NTOT); // quant loss
    out[NTOT + 3] = 0.f;                            // TAU2
  }
}

extern "C" void kernel_launch(void* const* d_in, const int* in_sizes, int n_in,
                              void* d_out, int out_size, void* d_ws, size_t ws_size,
                              hipStream_t stream) {
  const float* x    = (const float*)d_in[0];
  const float* bins = (const float*)d_in[1];
  float* out        = (float*)d_out;
  float* partials   = (float*)d_ws;                 // (K+1)*NB floats = 264 KB
  float* sums       = partials + (K + 1) * NB;      // 33 floats

  ssq_main  <<<NB,    TPB, 0, stream>>>(x, bins, out, partials);
  ssq_reduce<<<K + 1, TPB, 0, stream>>>(partials, sums);
  ssq_final <<<1,     64,  0, stream>>>(sums, out);
}